// Round 1
// baseline (234.292 us; speedup 1.0000x reference)
//
#include <hip/hip_runtime.h>

#define NCLS 1024
#define DIM  256
#define NTOT 2048   // 2*NCLS rows in "total"

__device__ __forceinline__ float4 f4add(float4 a, float4 b){
  return make_float4(a.x+b.x, a.y+b.y, a.z+b.z, a.w+b.w);
}

// ---------------- init: zero the accumulators we atomically add into ----------
__global__ void k_init(int* counts, float* s, double* sumsq, double* lossacc){
  int t = threadIdx.x;
  if (t < NCLS) counts[t] = 0;
  if (t < DIM)  s[t] = 0.f;
  if (t == 0){ *sumsq = 0.0; *lossacc = 0.0; }
}

// ---------------- histogram of targets (LDS-staged) ---------------------------
__global__ __launch_bounds__(256) void k_hist(const int* __restrict__ tgt, int n,
                                              int* __restrict__ counts){
  __shared__ int h[NCLS];
  for (int i = threadIdx.x; i < NCLS; i += blockDim.x) h[i] = 0;
  __syncthreads();
  for (int i = blockIdx.x*blockDim.x + threadIdx.x; i < n; i += gridDim.x*blockDim.x)
    atomicAdd(&h[tgt[i]], 1);
  __syncthreads();
  for (int i = threadIdx.x; i < NCLS; i += blockDim.x)
    if (h[i]) atomicAdd(&counts[i], h[i]);
}

// ---------------- exclusive scan over 1024 counts (single block) --------------
__global__ void k_scan(const int* __restrict__ counts, int* __restrict__ offsets,
                       int* __restrict__ cursor){
  __shared__ int buf[NCLS];
  int t = threadIdx.x;
  int v = counts[t];
  buf[t] = v;
  __syncthreads();
  for (int o = 1; o < NCLS; o <<= 1){
    int u = (t >= o) ? buf[t-o] : 0;
    __syncthreads();
    buf[t] += u;
    __syncthreads();
  }
  int excl = buf[t] - v;
  offsets[t] = excl;
  cursor[t]  = excl;
}

// ---------------- counting-sort scatter: per-class row lists ------------------
__global__ __launch_bounds__(256) void k_scatter(const int* __restrict__ tgt, int n,
                                                 int* __restrict__ cursor,
                                                 int* __restrict__ index){
  for (int i = blockIdx.x*blockDim.x + threadIdx.x; i < n; i += gridDim.x*blockDim.x){
    int t = tgt[i];
    int pos = atomicAdd(&cursor[t], 1);
    index[pos] = i;
  }
}

// ---------------- centers: one block per class --------------------------------
// Writes T[c] (rgb center) and T[NCLS+c] (ir center), row sq-norms, column sum s,
// and total sum of sq (for the closed-form bandwidth).
__global__ __launch_bounds__(256) void k_centers(const float* __restrict__ xr,
    const float* __restrict__ xi, const int* __restrict__ index,
    const int* __restrict__ counts, const int* __restrict__ offsets,
    float* __restrict__ T, float* __restrict__ sq, float* __restrict__ s,
    double* __restrict__ sumsq)
{
  int c   = blockIdx.x;
  int tid = threadIdx.x;
  int l = tid & 63;        // float4 column group (64*4 = 256 dims)
  int g = tid >> 6;        // row subgroup 0..3
  int cnt = counts[c], off = offsets[c];
  const float4* xr4 = (const float4*)xr;
  const float4* xi4 = (const float4*)xi;
  float4 ar = make_float4(0,0,0,0), ai = make_float4(0,0,0,0);
  for (int j = g; j < cnt; j += 4){
    int row = index[off + j];
    float4 vr = xr4[(long)row*64 + l];
    float4 vi = xi4[(long)row*64 + l];
    ar = f4add(ar, vr);
    ai = f4add(ai, vi);
  }
  __shared__ float4 sh[256];
  sh[tid] = ar; __syncthreads();
  float4 cr = make_float4(0,0,0,0);
  if (tid < 64) cr = f4add(f4add(sh[tid], sh[tid+64]), f4add(sh[tid+128], sh[tid+192]));
  __syncthreads();
  sh[tid] = ai; __syncthreads();
  if (tid < 64){
    float4 ci = f4add(f4add(sh[tid], sh[tid+64]), f4add(sh[tid+128], sh[tid+192]));
    float invd = 1.0f / fmaxf((float)cnt, 1.0f);
    cr.x *= invd; cr.y *= invd; cr.z *= invd; cr.w *= invd;
    ci.x *= invd; ci.y *= invd; ci.z *= invd; ci.w *= invd;
    ((float4*)T)[c*64 + tid]          = cr;
    ((float4*)T)[(NCLS + c)*64 + tid] = ci;
    atomicAdd(&s[tid*4+0], cr.x + ci.x);
    atomicAdd(&s[tid*4+1], cr.y + ci.y);
    atomicAdd(&s[tid*4+2], cr.z + ci.z);
    atomicAdd(&s[tid*4+3], cr.w + ci.w);
    float sr = cr.x*cr.x + cr.y*cr.y + cr.z*cr.z + cr.w*cr.w;
    float si = ci.x*ci.x + ci.y*ci.y + ci.z*ci.z + ci.w*ci.w;
    #pragma unroll
    for (int o = 32; o > 0; o >>= 1){
      sr += __shfl_down(sr, o);
      si += __shfl_down(si, o);
    }
    if (tid == 0){
      sq[c]        = sr;
      sq[NCLS + c] = si;
      atomicAdd(sumsq, (double)sr + (double)si);
    }
  }
}

// ---------------- closed-form bandwidth ---------------------------------------
// sum(dists) = 2n*sum(sq) - 2*||colsum||^2  (clamp affects only ~1e-6 diagonal noise)
__global__ void k_bw(const float* __restrict__ s, const double* __restrict__ sumsq,
                     float* __restrict__ invbw){
  double ss = 0.0;
  for (int d = 0; d < DIM; ++d){ double v = (double)s[d]; ss += v*v; }
  double S1 = 2.0*(double)NTOT*(*sumsq) - 2.0*ss;
  double bw = S1 / ((double)NTOT*(double)NTOT - (double)NTOT) / 4.0; // / KERNEL_MUL^(KN//2)
  #pragma unroll
  for (int k = 0; k < 5; ++k)
    invbw[k] = (float)(1.0 / (bw * (double)(1 << k)));
}

// ---------------- fused Gram + 5-exp kernel + signed reduction ----------------
__global__ __launch_bounds__(256) void k_mmd(const float* __restrict__ T,
    const float* __restrict__ sq, const float* __restrict__ invbw,
    double* __restrict__ lossacc)
{
  __shared__ float As[64][68];
  __shared__ float Bs[64][68];
  __shared__ float red[4];
  int bx = blockIdx.x, by = blockIdx.y;
  int tid = threadIdx.x;
  int tx = tid & 15, ty = tid >> 4;
  int rowA = by*64, rowB = bx*64;
  float acc[4][4];
  #pragma unroll
  for (int a = 0; a < 4; ++a)
    #pragma unroll
    for (int b = 0; b < 4; ++b) acc[a][b] = 0.f;

  for (int kk = 0; kk < DIM; kk += 64){
    #pragma unroll
    for (int it = 0; it < 4; ++it){
      int idx = it*256 + tid;
      int r = idx >> 4, c4 = idx & 15;
      float4 va = *(const float4*)&T[(rowA + r)*DIM + kk + c4*4];
      float4 vb = *(const float4*)&T[(rowB + r)*DIM + kk + c4*4];
      *(float4*)&As[r][c4*4] = va;
      *(float4*)&Bs[r][c4*4] = vb;
    }
    __syncthreads();
    #pragma unroll 8
    for (int k = 0; k < 64; ++k){
      float a0 = As[ty*4+0][k], a1 = As[ty*4+1][k], a2 = As[ty*4+2][k], a3 = As[ty*4+3][k];
      float b0 = Bs[tx*4+0][k], b1 = Bs[tx*4+1][k], b2 = Bs[tx*4+2][k], b3 = Bs[tx*4+3][k];
      acc[0][0] += a0*b0; acc[0][1] += a0*b1; acc[0][2] += a0*b2; acc[0][3] += a0*b3;
      acc[1][0] += a1*b0; acc[1][1] += a1*b1; acc[1][2] += a1*b2; acc[1][3] += a1*b3;
      acc[2][0] += a2*b0; acc[2][1] += a2*b1; acc[2][2] += a2*b2; acc[2][3] += a2*b3;
      acc[3][0] += a3*b0; acc[3][1] += a3*b1; acc[3][2] += a3*b2; acc[3][3] += a3*b3;
    }
    __syncthreads();
  }

  float i0 = invbw[0], i1 = invbw[1], i2 = invbw[2], i3 = invbw[3], i4 = invbw[4];
  float lacc = 0.f;
  #pragma unroll
  for (int a = 0; a < 4; ++a){
    int i = rowA + ty*4 + a;
    float sqi  = sq[i];
    float sgnI = (i < NCLS) ? 1.f : -1.f;
    #pragma unroll
    for (int b = 0; b < 4; ++b){
      int j = rowB + tx*4 + b;
      float d = sqi + sq[j] - 2.f*acc[a][b];
      d = fmaxf(d, 0.f);
      float w = __expf(-d*i0) + __expf(-d*i1) + __expf(-d*i2) + __expf(-d*i3) + __expf(-d*i4);
      lacc += ((j < NCLS) ? sgnI : -sgnI) * w;
    }
  }
  #pragma unroll
  for (int o = 32; o > 0; o >>= 1) lacc += __shfl_down(lacc, o);
  int lane = tid & 63, wid = tid >> 6;
  if (lane == 0) red[wid] = lacc;
  __syncthreads();
  if (tid == 0) atomicAdd(lossacc, (double)(red[0]+red[1]+red[2]+red[3]));
}

__global__ void k_final(const double* __restrict__ lossacc, float* __restrict__ out){
  out[0] = (float)(*lossacc * (1.0 / ((double)NCLS * (double)NCLS)));
}

extern "C" void kernel_launch(void* const* d_in, const int* in_sizes, int n_in,
                              void* d_out, int out_size, void* d_ws, size_t ws_size,
                              hipStream_t stream) {
  const float* xr  = (const float*)d_in[0];
  const float* xi  = (const float*)d_in[1];
  const int*   tgt = (const int*)d_in[2];
  float* out = (float*)d_out;
  int n = in_sizes[2];                 // 131072 rows

  char* w = (char*)d_ws;
  int* counts   = (int*)w;                      // 1024
  int* offsets  = counts + NCLS;                // 1024
  int* cursor   = offsets + NCLS;               // 1024
  int* index    = cursor + NCLS;                // n
  float* T      = (float*)(index + n);          // 2048*256  (16B aligned)
  float* sq     = T + NTOT*DIM;                 // 2048
  float* s      = sq + NTOT;                    // 256
  float* invbw  = s + DIM;                      // 5 (+3 pad)
  double* sumsq = (double*)(invbw + 8);         // 1
  double* lossd = sumsq + 1;                    // 1

  k_init<<<1, 1024, 0, stream>>>(counts, s, sumsq, lossd);
  k_hist<<<256, 256, 0, stream>>>(tgt, n, counts);
  k_scan<<<1, 1024, 0, stream>>>(counts, offsets, cursor);
  k_scatter<<<256, 256, 0, stream>>>(tgt, n, cursor, index);
  k_centers<<<NCLS, 256, 0, stream>>>(xr, xi, index, counts, offsets, T, sq, s, sumsq);
  k_bw<<<1, 1, 0, stream>>>(s, sumsq, invbw);
  k_mmd<<<dim3(32, 32), 256, 0, stream>>>(T, sq, invbw, lossd);
  k_final<<<1, 1, 0, stream>>>(lossd, out);
}

// Round 2
// 222.651 us; speedup vs baseline: 1.0523x; 1.0523x over previous
//
#include <hip/hip_runtime.h>

#define NCLS 1024
#define DIM  256
#define NTOT 2048   // 2*NCLS rows in "total"
#define IDXCHUNK 512

__device__ __forceinline__ float4 f4add(float4 a, float4 b){
  return make_float4(a.x+b.x, a.y+b.y, a.z+b.z, a.w+b.w);
}

// ---------------- init: zero the accumulators we atomically add into ----------
__global__ void k_init(int* counts, float* s, double* sumsq, double* lossacc){
  int t = threadIdx.x;
  if (t < NCLS) counts[t] = 0;
  if (t < DIM)  s[t] = 0.f;
  if (t == 0){ *sumsq = 0.0; *lossacc = 0.0; }
}

// ---------------- histogram of targets (LDS-staged) ---------------------------
__global__ __launch_bounds__(256) void k_hist(const int* __restrict__ tgt, int n,
                                              int* __restrict__ counts){
  __shared__ int h[NCLS];
  for (int i = threadIdx.x; i < NCLS; i += blockDim.x) h[i] = 0;
  __syncthreads();
  for (int i = blockIdx.x*blockDim.x + threadIdx.x; i < n; i += gridDim.x*blockDim.x)
    atomicAdd(&h[tgt[i]], 1);
  __syncthreads();
  for (int i = threadIdx.x; i < NCLS; i += blockDim.x)
    if (h[i]) atomicAdd(&counts[i], h[i]);
}

// ---------------- exclusive scan over 1024 counts (single block) --------------
__global__ void k_scan(const int* __restrict__ counts, int* __restrict__ offsets,
                       int* __restrict__ cursor){
  __shared__ int buf[NCLS];
  int t = threadIdx.x;
  int v = counts[t];
  buf[t] = v;
  __syncthreads();
  for (int o = 1; o < NCLS; o <<= 1){
    int u = (t >= o) ? buf[t-o] : 0;
    __syncthreads();
    buf[t] += u;
    __syncthreads();
  }
  int excl = buf[t] - v;
  offsets[t] = excl;
  cursor[t]  = excl;
}

// ---------------- counting-sort scatter: per-class row lists ------------------
__global__ __launch_bounds__(256) void k_scatter(const int* __restrict__ tgt, int n,
                                                 int* __restrict__ cursor,
                                                 int* __restrict__ index){
  for (int i = blockIdx.x*blockDim.x + threadIdx.x; i < n; i += gridDim.x*blockDim.x){
    int t = tgt[i];
    int pos = atomicAdd(&cursor[t], 1);
    index[pos] = i;
  }
}

// ---------------- centers: one block per class --------------------------------
// LDS-staged index list + 4-row unrolled gather: 8 independent float4 loads in
// flight per wave -> BW-bound instead of latency-bound.
__global__ __launch_bounds__(256) void k_centers(const float* __restrict__ xr,
    const float* __restrict__ xi, const int* __restrict__ index,
    const int* __restrict__ counts, const int* __restrict__ offsets,
    float* __restrict__ T, float* __restrict__ sq, float* __restrict__ s,
    double* __restrict__ sumsq)
{
  int c   = blockIdx.x;
  int tid = threadIdx.x;
  int l = tid & 63;        // float4 column group (64*4 = 256 dims)
  int g = tid >> 6;        // row subgroup 0..3
  int cnt = counts[c], off = offsets[c];
  const float4* xr4 = (const float4*)xr;
  const float4* xi4 = (const float4*)xi;
  __shared__ int idx_sh[IDXCHUNK];
  float4 ar = make_float4(0,0,0,0), ai = make_float4(0,0,0,0);

  for (int base = 0; base < cnt; base += IDXCHUNK){
    int m = cnt - base; if (m > IDXCHUNK) m = IDXCHUNK;
    __syncthreads();
    for (int i = tid; i < m; i += 256) idx_sh[i] = index[off + base + i];
    __syncthreads();
    int j = g;
    // 4-row unroll: 8 independent 16B loads in flight
    for (; j + 12 < m; j += 16){
      long r0 = idx_sh[j], r1 = idx_sh[j+4], r2 = idx_sh[j+8], r3 = idx_sh[j+12];
      float4 a0 = xr4[r0*64 + l];
      float4 a1 = xr4[r1*64 + l];
      float4 a2 = xr4[r2*64 + l];
      float4 a3 = xr4[r3*64 + l];
      float4 b0 = xi4[r0*64 + l];
      float4 b1 = xi4[r1*64 + l];
      float4 b2 = xi4[r2*64 + l];
      float4 b3 = xi4[r3*64 + l];
      ar = f4add(ar, f4add(f4add(a0, a1), f4add(a2, a3)));
      ai = f4add(ai, f4add(f4add(b0, b1), f4add(b2, b3)));
    }
    for (; j < m; j += 4){
      long r = idx_sh[j];
      ar = f4add(ar, xr4[r*64 + l]);
      ai = f4add(ai, xi4[r*64 + l]);
    }
  }

  __shared__ float4 sh[256];
  sh[tid] = ar; __syncthreads();
  float4 cr = make_float4(0,0,0,0);
  if (tid < 64) cr = f4add(f4add(sh[tid], sh[tid+64]), f4add(sh[tid+128], sh[tid+192]));
  __syncthreads();
  sh[tid] = ai; __syncthreads();
  if (tid < 64){
    float4 ci = f4add(f4add(sh[tid], sh[tid+64]), f4add(sh[tid+128], sh[tid+192]));
    float invd = 1.0f / fmaxf((float)cnt, 1.0f);
    cr.x *= invd; cr.y *= invd; cr.z *= invd; cr.w *= invd;
    ci.x *= invd; ci.y *= invd; ci.z *= invd; ci.w *= invd;
    ((float4*)T)[c*64 + tid]          = cr;
    ((float4*)T)[(NCLS + c)*64 + tid] = ci;
    atomicAdd(&s[tid*4+0], cr.x + ci.x);
    atomicAdd(&s[tid*4+1], cr.y + ci.y);
    atomicAdd(&s[tid*4+2], cr.z + ci.z);
    atomicAdd(&s[tid*4+3], cr.w + ci.w);
    float sr = cr.x*cr.x + cr.y*cr.y + cr.z*cr.z + cr.w*cr.w;
    float si = ci.x*ci.x + ci.y*ci.y + ci.z*ci.z + ci.w*ci.w;
    #pragma unroll
    for (int o = 32; o > 0; o >>= 1){
      sr += __shfl_down(sr, o);
      si += __shfl_down(si, o);
    }
    if (tid == 0){
      sq[c]        = sr;
      sq[NCLS + c] = si;
      atomicAdd(sumsq, (double)sr + (double)si);
    }
  }
}

// ---------------- closed-form bandwidth ---------------------------------------
// sum(dists) = 2n*sum(sq) - 2*||colsum||^2  (clamp affects only ~1e-6 diagonal noise)
__global__ void k_bw(const float* __restrict__ s, const double* __restrict__ sumsq,
                     float* __restrict__ invbw){
  double ss = 0.0;
  for (int d = 0; d < DIM; ++d){ double v = (double)s[d]; ss += v*v; }
  double S1 = 2.0*(double)NTOT*(*sumsq) - 2.0*ss;
  double bw = S1 / ((double)NTOT*(double)NTOT - (double)NTOT) / 4.0; // / KERNEL_MUL^(KN//2)
  #pragma unroll
  for (int k = 0; k < 5; ++k)
    invbw[k] = (float)(1.0 / (bw * (double)(1 << k)));
}

// ---------------- fused Gram + 5-exp kernel + signed reduction ----------------
__global__ __launch_bounds__(256) void k_mmd(const float* __restrict__ T,
    const float* __restrict__ sq, const float* __restrict__ invbw,
    double* __restrict__ lossacc)
{
  __shared__ float As[64][68];
  __shared__ float Bs[64][68];
  __shared__ float red[4];
  int bx = blockIdx.x, by = blockIdx.y;
  int tid = threadIdx.x;
  int tx = tid & 15, ty = tid >> 4;
  int rowA = by*64, rowB = bx*64;
  float acc[4][4];
  #pragma unroll
  for (int a = 0; a < 4; ++a)
    #pragma unroll
    for (int b = 0; b < 4; ++b) acc[a][b] = 0.f;

  for (int kk = 0; kk < DIM; kk += 64){
    #pragma unroll
    for (int it = 0; it < 4; ++it){
      int idx = it*256 + tid;
      int r = idx >> 4, c4 = idx & 15;
      float4 va = *(const float4*)&T[(rowA + r)*DIM + kk + c4*4];
      float4 vb = *(const float4*)&T[(rowB + r)*DIM + kk + c4*4];
      *(float4*)&As[r][c4*4] = va;
      *(float4*)&Bs[r][c4*4] = vb;
    }
    __syncthreads();
    #pragma unroll 8
    for (int k = 0; k < 64; ++k){
      float a0 = As[ty*4+0][k], a1 = As[ty*4+1][k], a2 = As[ty*4+2][k], a3 = As[ty*4+3][k];
      float b0 = Bs[tx*4+0][k], b1 = Bs[tx*4+1][k], b2 = Bs[tx*4+2][k], b3 = Bs[tx*4+3][k];
      acc[0][0] += a0*b0; acc[0][1] += a0*b1; acc[0][2] += a0*b2; acc[0][3] += a0*b3;
      acc[1][0] += a1*b0; acc[1][1] += a1*b1; acc[1][2] += a1*b2; acc[1][3] += a1*b3;
      acc[2][0] += a2*b0; acc[2][1] += a2*b1; acc[2][2] += a2*b2; acc[2][3] += a2*b3;
      acc[3][0] += a3*b0; acc[3][1] += a3*b1; acc[3][2] += a3*b2; acc[3][3] += a3*b3;
    }
    __syncthreads();
  }

  float i0 = invbw[0], i1 = invbw[1], i2 = invbw[2], i3 = invbw[3], i4 = invbw[4];
  float lacc = 0.f;
  #pragma unroll
  for (int a = 0; a < 4; ++a){
    int i = rowA + ty*4 + a;
    float sqi  = sq[i];
    float sgnI = (i < NCLS) ? 1.f : -1.f;
    #pragma unroll
    for (int b = 0; b < 4; ++b){
      int j = rowB + tx*4 + b;
      float d = sqi + sq[j] - 2.f*acc[a][b];
      d = fmaxf(d, 0.f);
      float w = __expf(-d*i0) + __expf(-d*i1) + __expf(-d*i2) + __expf(-d*i3) + __expf(-d*i4);
      lacc += ((j < NCLS) ? sgnI : -sgnI) * w;
    }
  }
  #pragma unroll
  for (int o = 32; o > 0; o >>= 1) lacc += __shfl_down(lacc, o);
  int lane = tid & 63, wid = tid >> 6;
  if (lane == 0) red[wid] = lacc;
  __syncthreads();
  if (tid == 0) atomicAdd(lossacc, (double)(red[0]+red[1]+red[2]+red[3]));
}

__global__ void k_final(const double* __restrict__ lossacc, float* __restrict__ out){
  out[0] = (float)(*lossacc * (1.0 / ((double)NCLS * (double)NCLS)));
}

extern "C" void kernel_launch(void* const* d_in, const int* in_sizes, int n_in,
                              void* d_out, int out_size, void* d_ws, size_t ws_size,
                              hipStream_t stream) {
  const float* xr  = (const float*)d_in[0];
  const float* xi  = (const float*)d_in[1];
  const int*   tgt = (const int*)d_in[2];
  float* out = (float*)d_out;
  int n = in_sizes[2];                 // 131072 rows

  char* w = (char*)d_ws;
  int* counts   = (int*)w;                      // 1024
  int* offsets  = counts + NCLS;                // 1024
  int* cursor   = offsets + NCLS;               // 1024
  int* index    = cursor + NCLS;                // n
  float* T      = (float*)(index + n);          // 2048*256  (16B aligned)
  float* sq     = T + NTOT*DIM;                 // 2048
  float* s      = sq + NTOT;                    // 256
  float* invbw  = s + DIM;                      // 5 (+3 pad)
  double* sumsq = (double*)(invbw + 8);         // 1
  double* lossd = sumsq + 1;                    // 1

  k_init<<<1, 1024, 0, stream>>>(counts, s, sumsq, lossd);
  k_hist<<<256, 256, 0, stream>>>(tgt, n, counts);
  k_scan<<<1, 1024, 0, stream>>>(counts, offsets, cursor);
  k_scatter<<<256, 256, 0, stream>>>(tgt, n, cursor, index);
  k_centers<<<NCLS, 256, 0, stream>>>(xr, xi, index, counts, offsets, T, sq, s, sumsq);
  k_bw<<<1, 1, 0, stream>>>(s, sumsq, invbw);
  k_mmd<<<dim3(32, 32), 256, 0, stream>>>(T, sq, invbw, lossd);
  k_final<<<1, 1, 0, stream>>>(lossd, out);
}